// Round 1
// 216.681 us; speedup vs baseline: 1.0213x; 1.0213x over previous
//
#include <hip/hip_runtime.h>
#include <math.h>

#define BB  4
#define SS  1024
#define DD  512
#define HH  8
#define DHD 64
#define PL  2097152      // elements per Q/K/V/Ob plane (also B*S*D)
#define WPL 262144       // elements per W plane

constexpr float LN_EPS = 1e-5f;

using half4 = __attribute__((ext_vector_type(4))) _Float16;
using half8 = __attribute__((ext_vector_type(8))) _Float16;
using f32x4 = __attribute__((ext_vector_type(4))) float;

__device__ __forceinline__ half8 negh(half8 a) {
    union { half8 h; unsigned int u[4]; } t;
    t.h = a;
    #pragma unroll
    for (int i = 0; i < 4; ++i) t.u[i] ^= 0x80008000u;
    return t.h;
}
// 64-wide swizzled rows (XOR (row&7)<<3, 8-half granules): conflict-free b128
__device__ __forceinline__ half8 ldh64(const unsigned short* p, int row, int col) {
    return *(const half8*)(p + row * 64 + (col ^ ((row & 7) << 3)));
}
#define MFMA16(acc, a, b) acc = __builtin_amdgcn_mfma_f32_16x16x32_f16(a, b, acc, 0, 0, 0)

// ---------------------------------------------------------------------------
// Kernel 0: fp32 complex -> fp16 r/i planes (used for q/k/v inputs and W).
// ---------------------------------------------------------------------------
__global__ __launch_bounds__(256)
void cvt_kernel(const float2* __restrict__ s0, const float2* __restrict__ s1,
                const float2* __restrict__ s2, unsigned short* __restrict__ dst,
                int planeElems) {
    const int z = blockIdx.y;
    const float2* src = z == 0 ? s0 : (z == 1 ? s1 : s2);
    unsigned short* base = dst + (size_t)z * 2 * planeElems;
    const int idx = (blockIdx.x * 256 + threadIdx.x) * 2;   // complex index
    float4 t = *(const float4*)(src + idx);
    union { _Float16 h[2]; unsigned int u; } r, i;
    r.h[0] = (_Float16)t.x; r.h[1] = (_Float16)t.z;
    i.h[0] = (_Float16)t.y; i.h[1] = (_Float16)t.w;
    ((unsigned int*)(base))[idx >> 1] = r.u;
    ((unsigned int*)(base + planeElems))[idx >> 1] = i.u;
}

// ---------------------------------------------------------------------------
// Kernel 1: complex projection.
// 128x128 tile, 4 waves in 2x2 (each wave a 64x64 square sub-tile -> 4 MFMA
// per staged fragment-pair, 128 MFMA vs 32 ds_read_b128 per wave per K-step).
// 2-phase double-buffered async staging: wave w DMAs plane w (Xr/Xi/Wr/Wi)
// via global_load_lds width-16 with PRE-SWIZZLED SOURCE + linear LDS dest, so
// the swizzled ldh64 read pattern (proven conflict-free) is preserved.
// One barrier per K-step (the __syncthreads vmcnt-drain doubles as the
// prefetch wait). -Wi folded into the B fragment (negh once per et).
// ---------------------------------------------------------------------------
__global__ __launch_bounds__(256, 1)
void proj_kernel(const unsigned short* __restrict__ XP,
                 const unsigned short* __restrict__ WP,
                 const float2* __restrict__ bq, const float2* __restrict__ bk,
                 const float2* __restrict__ bv,
                 unsigned short* __restrict__ QG, unsigned short* __restrict__ KG,
                 unsigned short* __restrict__ VG) {
    const unsigned short* XR = XP + (size_t)blockIdx.z * 2 * PL;
    const unsigned short* XI = XR + PL;
    const unsigned short* WRp = WP + (size_t)blockIdx.z * 2 * WPL;
    const unsigned short* WIp = WRp + WPL;
    const float2* bias; unsigned short* outP;
    if (blockIdx.z == 0)      { bias = bq; outP = QG; }
    else if (blockIdx.z == 1) { bias = bk; outP = KG; }
    else                      { bias = bv; outP = VG; }
    const bool isV = (blockIdx.z == 2);

    // [buf][plane][128 rows][64 k] fp16, 64-half rows, LINEAR (swizzle is in
    // the global source address). 2*(32K + 32K) = 128 KiB.
    __shared__ __align__(16) unsigned short Xs[2][2][128 * 64];
    __shared__ __align__(16) unsigned short Ws[2][2][128 * 64];

    const int tid  = threadIdx.x;
    const int w    = tid >> 6;
    const int lane = tid & 63;
    const int quad = lane >> 4;
    const int l15  = lane & 15;
    const int wm   = w >> 1;                 // m half of the 128x128 tile
    const int we   = w & 1;                  // e half
    const int m0   = blockIdx.x * 128;
    const int e0   = blockIdx.y * 128;

    // ---- staging setup: wave w owns one plane; 16 DMA instrs / K-step ----
    // lane -> (row-in-8group, granule); source granule pre-swizzled so that
    // the linear LDS slot (row, g) holds global granule (g ^ (row&7)).
    const int srow = lane >> 3;              // 0..7
    const int sg   = lane & 7;
    const int scol = ((sg ^ srow) << 3);     // halfs
    const unsigned short* gplane;
    unsigned short* l0p; unsigned short* l1p;
    int row0;
    if (w == 0)      { gplane = XR;  row0 = m0; l0p = &Xs[0][0][0]; l1p = &Xs[1][0][0]; }
    else if (w == 1) { gplane = XI;  row0 = m0; l0p = &Xs[0][1][0]; l1p = &Xs[1][1][0]; }
    else if (w == 2) { gplane = WRp; row0 = e0; l0p = &Ws[0][0][0]; l1p = &Ws[1][0][0]; }
    else             { gplane = WIp; row0 = e0; l0p = &Ws[0][1][0]; l1p = &Ws[1][1][0]; }
    const unsigned short* gs = gplane + (size_t)(row0 + srow) * DD + scol;

#define STAGE(LB, DC) { \
        const unsigned short* _g = gs + (DC); \
        _Pragma("unroll") \
        for (int j = 0; j < 16; ++j) \
            __builtin_amdgcn_global_load_lds( \
                (const __attribute__((address_space(1))) void*)(_g + j * 8 * DD), \
                (__attribute__((address_space(3))) void*)((LB) + j * 512), \
                16, 0, 0); \
    }

    f32x4 Sr[4][4], Si[4][4];                // [mf][ef]
    #pragma unroll
    for (int a = 0; a < 4; ++a)
        #pragma unroll
        for (int c = 0; c < 4; ++c) { Sr[a][c] = (f32x4)0.f; Si[a][c] = (f32x4)0.f; }

    STAGE(l0p, 0);
    __syncthreads();                          // drains vmcnt -> buf0 ready

    #pragma unroll 2
    for (int s = 0; s < 8; ++s) {
        if (s < 7) STAGE(((s & 1) ? l0p : l1p), (s + 1) * 64);   // prefetch next

        const unsigned short* xb0 = &Xs[s & 1][0][0];
        const unsigned short* xb1 = &Xs[s & 1][1][0];
        const unsigned short* wb0 = &Ws[s & 1][0][0];
        const unsigned short* wb1 = &Ws[s & 1][1][0];

        #pragma unroll
        for (int kc = 0; kc < 2; ++kc) {
            const int dl = kc * 32 + quad * 8;
            half8 xr[4], xi[4];
            #pragma unroll
            for (int mf = 0; mf < 4; ++mf) {
                const int mr = wm * 64 + mf * 16 + l15;
                xr[mf] = ldh64(xb0, mr, dl);
                xi[mf] = ldh64(xb1, mr, dl);
            }
            #pragma unroll
            for (int ef = 0; ef < 4; ++ef) {
                const int er = we * 64 + ef * 16 + l15;
                half8 wr  = ldh64(wb0, er, dl);
                half8 wi  = ldh64(wb1, er, dl);
                half8 wmi = negh(wi);
                #pragma unroll
                for (int mf = 0; mf < 4; ++mf) {
                    MFMA16(Sr[mf][ef], xr[mf], wr);    // Xr.Wr
                    MFMA16(Sr[mf][ef], xi[mf], wmi);   // -Xi.Wi
                    MFMA16(Si[mf][ef], xr[mf], wi);    // Xr.Wi
                    MFMA16(Si[mf][ef], xi[mf], wr);    // Xi.Wr
                }
            }
        }
        __syncthreads();   // drains this wave's prefetch vmcnt + frees buf
    }
#undef STAGE

    // ---- epilogue: + bias, fp16, write planes (V transposed) ----
    #pragma unroll
    for (int ef = 0; ef < 4; ++ef) {
        const int eg  = e0 + we * 64 + ef * 16 + l15;   // global out column
        const int hh  = eg >> 6;                         // head
        const int col = eg & 63;
        float2 bb = bias[eg];
        #pragma unroll
        for (int mf = 0; mf < 4; ++mf) {
            #pragma unroll
            for (int reg = 0; reg < 4; ++reg) {
                int m = m0 + wm * 64 + mf * 16 + quad * 4 + reg;
                int bidx = m >> 10;
                int sidx = m & 1023;
                int bh = bidx * HH + hh;
                union { _Float16 h; unsigned short u; } cr, ci;
                cr.h = (_Float16)(Sr[mf][ef][reg] + bb.x);
                ci.h = (_Float16)(Si[mf][ef][reg] + bb.y);
                size_t o = isV ? ((size_t)bh * DHD + col) * SS + sidx
                               : ((size_t)bh * SS + sidx) * DHD + col;
                outP[0 * PL + o] = cr.u;
                outP[1 * PL + o] = ci.u;
            }
        }
    }
}

// ---------------------------------------------------------------------------
// Kernel 2: fp16 MFMA flash attention, S^T formulation. (unchanged)
// ---------------------------------------------------------------------------
#define AWID 72
__global__ __launch_bounds__(256, 2)
void attn_kernel(const unsigned short* __restrict__ QG, const unsigned short* __restrict__ KG,
                 const unsigned short* __restrict__ VG,
                 unsigned short* __restrict__ ObR, unsigned short* __restrict__ ObI) {
    __shared__ unsigned short Ks[2][64 * AWID];   // [r,i][k][d]
    __shared__ unsigned short Vt[2][64 * AWID];   // [r,i][d][k]
    __shared__ unsigned short Ps[2][64 * AWID];   // [r,i][q][k]
    __shared__ float lbuf[2][2][64];              // [plane][k-half][q]

    const int n   = blockIdx.x;
    const int bh  = (n & 7) * 4 + (n >> 7);       // XCD-local bh group
    const int q0  = ((n >> 3) & 15) * 64;
    const int b   = bh >> 3;
    const int h   = bh & 7;

    const int tid  = threadIdx.x;
    const int w    = tid >> 6;
    const int lane = tid & 63;
    const int quad = lane >> 4;
    const int l15  = lane & 15;
    const int sw   = w & 1;        // q-half (both phases)
    const int tw   = w >> 1;       // k-half (scores) / d-half (PV)

    // Q in B-layout registers: lane = q col, quad*8+j = d within 32-window
    half8 qfr[2][2], qfi[2][2], qfmi[2][2];       // [qt][kc]
    #pragma unroll
    for (int qt = 0; qt < 2; ++qt)
        #pragma unroll
        for (int kc = 0; kc < 2; ++kc) {
            size_t qa = ((size_t)bh * SS + q0 + sw * 32 + qt * 16 + l15) * DHD + kc * 32 + quad * 8;
            qfr[qt][kc]  = *(const half8*)(QG + qa);
            qfi[qt][kc]  = *(const half8*)(QG + PL + qa);
            qfmi[qt][kc] = negh(qfi[qt][kc]);
        }

    f32x4 acc[2][2][4];            // [qt][dt][PrVr,PrVi,PiVr,PiVi]
    #pragma unroll
    for (int qt = 0; qt < 2; ++qt)
        #pragma unroll
        for (int dt = 0; dt < 2; ++dt)
            #pragma unroll
            for (int p = 0; p < 4; ++p) acc[qt][dt][p] = (f32x4)0.f;
    float lacc[2][2] = {{0.f, 0.f}, {0.f, 0.f}};  // [qt][plane]

    const int srow = tid >> 3;      // 0..31
    const int sg   = (tid & 7) * 8; // granule col

    for (int kt = 0; kt < SS; kt += 64) {
        __syncthreads();
        // ---- stage K [64k][64d] and V^T [64d][64k] (one row per 8 lanes) ----
        #pragma unroll
        for (int p = 0; p < 2; ++p)
            #pragma unroll
            for (int it = 0; it < 2; ++it) {
                const int r = it * 32 + srow;
                *(uint4*)&Ks[p][r * AWID + sg] =
                    *(const uint4*)(KG + (size_t)p * PL + ((size_t)bh * SS + kt + r) * DHD + sg);
                *(uint4*)&Vt[p][r * AWID + sg] =
                    *(const uint4*)(VG + (size_t)p * PL + ((size_t)bh * DHD + r) * SS + kt + sg);
            }
        __syncthreads();

        // ---- scores: S^T[k32][q32] for this wave's (tw k-half, sw q-half) ----
        f32x4 Sr[2][2], Si[2][2];   // [kt2][qt]
        #pragma unroll
        for (int a = 0; a < 2; ++a)
            #pragma unroll
            for (int c = 0; c < 2; ++c) { Sr[a][c] = (f32x4)0.f; Si[a][c] = (f32x4)0.f; }
        #pragma unroll
        for (int kc = 0; kc < 2; ++kc) {
            #pragma unroll
            for (int kt2 = 0; kt2 < 2; ++kt2) {
                const int krow = tw * 32 + kt2 * 16 + l15;
                half8 akr = *(const half8*)&Ks[0][krow * AWID + kc * 32 + quad * 8];
                half8 aki = *(const half8*)&Ks[1][krow * AWID + kc * 32 + quad * 8];
                #pragma unroll
                for (int qt = 0; qt < 2; ++qt) {
                    MFMA16(Sr[kt2][qt], akr, qfr[qt][kc]);    // K_r . Q_r
                    MFMA16(Sr[kt2][qt], aki, qfmi[qt][kc]);   // -K_i . Q_i
                    MFMA16(Si[kt2][qt], aki, qfr[qt][kc]);    // K_i . Q_r
                    MFMA16(Si[kt2][qt], akr, qfi[qt][kc]);    // K_r . Q_i
                }
            }
        }

        // ---- exp -> P (b64 packed, q-major), l partial per lane ----
        #pragma unroll
        for (int kt2 = 0; kt2 < 2; ++kt2)
            #pragma unroll
            for (int qt = 0; qt < 2; ++qt) {
                half4 pr, pi;
                float sr_ = 0.f, si_ = 0.f;
                #pragma unroll
                for (int reg = 0; reg < 4; ++reg) {
                    float er = __expf(Sr[kt2][qt][reg] * 0.125f);
                    float ei = __expf(Si[kt2][qt][reg] * 0.125f);
                    pr[reg] = (_Float16)er;
                    pi[reg] = (_Float16)ei;
                    sr_ += (float)pr[reg];   // l from rounded p: consistent weights
                    si_ += (float)pi[reg];
                }
                lacc[qt][0] += sr_;
                lacc[qt][1] += si_;
                const int qrow = sw * 32 + qt * 16 + l15;
                const int kcol = tw * 32 + kt2 * 16 + quad * 4;
                *(half4*)&Ps[0][qrow * AWID + kcol] = pr;
                *(half4*)&Ps[1][qrow * AWID + kcol] = pi;
            }
        __syncthreads();

        // ---- PV: out tile q32 (sw) x d32 (tw), k64 accumulation ----
        #pragma unroll
        for (int kc = 0; kc < 2; ++kc) {
            half8 ap[2][2];   // [qt][plane]
            #pragma unroll
            for (int qt = 0; qt < 2; ++qt) {
                const int qrow = sw * 32 + qt * 16 + l15;
                ap[qt][0] = *(const half8*)&Ps[0][qrow * AWID + kc * 32 + quad * 8];
                ap[qt][1] = *(const half8*)&Ps[1][qrow * AWID + kc * 32 + quad * 8];
            }
            #pragma unroll
            for (int dt = 0; dt < 2; ++dt) {
                const int drow = tw * 32 + dt * 16 + l15;
                half8 bvr = *(const half8*)&Vt[0][drow * AWID + kc * 32 + quad * 8];
                half8 bvi = *(const half8*)&Vt[1][drow * AWID + kc * 32 + quad * 8];
                #pragma unroll
                for (int qt = 0; qt < 2; ++qt) {
                    MFMA16(acc[qt][dt][0], ap[qt][0], bvr);
                    MFMA16(acc[qt][dt][1], ap[qt][0], bvi);
                    MFMA16(acc[qt][dt][2], ap[qt][1], bvr);
                    MFMA16(acc[qt][dt][3], ap[qt][1], bvi);
                }
            }
        }
    }

    // ---- combine l: quad-reduce (lane's k-subset -> full k-half), store ----
    __syncthreads();
    #pragma unroll
    for (int qt = 0; qt < 2; ++qt)
        #pragma unroll
        for (int p = 0; p < 2; ++p) {
            float v = lacc[qt][p];
            v += __shfl_xor(v, 16);
            v += __shfl_xor(v, 32);
            if (lane < 16) lbuf[p][tw][sw * 32 + qt * 16 + lane] = v;
        }
    __syncthreads();

    // ---- epilogue: normalize, combine complex, store fp16 planes ----
    #pragma unroll
    for (int qt = 0; qt < 2; ++qt)
        #pragma unroll
        for (int reg = 0; reg < 4; ++reg) {
            const int qloc = sw * 32 + qt * 16 + quad * 4 + reg;
            const float ir = 1.f / (lbuf[0][0][qloc] + lbuf[0][1][qloc]);
            const float ii = 1.f / (lbuf[1][0][qloc] + lbuf[1][1][qloc]);
            #pragma unroll
            for (int dt = 0; dt < 2; ++dt) {
                const int d = tw * 32 + dt * 16 + l15;
                union { _Float16 h; unsigned short u; } cr, ci;
                cr.h = (_Float16)(acc[qt][dt][0][reg] * ir - acc[qt][dt][3][reg] * ii);
                ci.h = (_Float16)(acc[qt][dt][1][reg] * ir + acc[qt][dt][2][reg] * ii);
                size_t o = ((size_t)b * SS + q0 + qloc) * DD + h * DHD + d;
                ObR[o] = cr.u;
                ObI[o] = ci.u;
            }
        }
}

// ---------------------------------------------------------------------------
// Kernel 3: residual + dual LayerNorm over D (biased var, eps inside sqrt)
// ---------------------------------------------------------------------------
__global__ __launch_bounds__(256)
void ln_kernel(const unsigned short* __restrict__ OrP, const unsigned short* __restrict__ OiP,
               const float2* __restrict__ Qin,
               const float* __restrict__ gr, const float* __restrict__ br,
               const float* __restrict__ gi, const float* __restrict__ bi,
               float2* __restrict__ out) {
    const int row = blockIdx.x;           // b*S + s
    const int tid = threadIdx.x;
    const size_t base = (size_t)row * DD;
    const int e0 = 2 * tid, e1 = 2 * tid + 1;

    union { unsigned int u; _Float16 h[2]; } tr, ti;
    tr.u = *(const unsigned int*)(OrP + base + e0);
    ti.u = *(const unsigned int*)(OiP + base + e0);
    float2 r0 = Qin[base + e0];
    float2 r1 = Qin[base + e1];
    float xr0 = (float)tr.h[0] + r0.x;
    float xr1 = (float)tr.h[1] + r1.x;
    float xi0 = (float)ti.h[0] + r0.y;
    float xi1 = (float)ti.h[1] + r1.y;

    float sr = xr0 + xr1;
    float si = xi0 + xi1;
    float qr = xr0 * xr0 + xr1 * xr1;
    float qi = xi0 * xi0 + xi1 * xi1;
    #pragma unroll
    for (int off = 32; off > 0; off >>= 1) {
        sr += __shfl_down(sr, off);
        si += __shfl_down(si, off);
        qr += __shfl_down(qr, off);
        qi += __shfl_down(qi, off);
    }
    __shared__ float red[4][4];
    __shared__ float stat[4];
    int lane = tid & 63, wid = tid >> 6;
    if (lane == 0) { red[wid][0] = sr; red[wid][1] = si; red[wid][2] = qr; red[wid][3] = qi; }
    __syncthreads();
    if (tid == 0) {
        sr = red[0][0] + red[1][0] + red[2][0] + red[3][0];
        si = red[0][1] + red[1][1] + red[2][1] + red[3][1];
        qr = red[0][2] + red[1][2] + red[2][2] + red[3][2];
        qi = red[0][3] + red[1][3] + red[2][3] + red[3][3];
        float mur = sr * (1.f / DD), mui = si * (1.f / DD);
        float vr = qr * (1.f / DD) - mur * mur;
        float vi = qi * (1.f / DD) - mui * mui;
        stat[0] = mur; stat[1] = mui;
        stat[2] = rsqrtf(vr + LN_EPS); stat[3] = rsqrtf(vi + LN_EPS);
    }
    __syncthreads();
    float mur = stat[0], mui = stat[1], rsr = stat[2], rsi = stat[3];
    out[base + e0] = make_float2((xr0 - mur) * rsr * gr[e0] + br[e0],
                                 (xi0 - mui) * rsi * gi[e0] + bi[e0]);
    out[base + e1] = make_float2((xr1 - mur) * rsr * gr[e1] + br[e1],
                                 (xi1 - mui) * rsi * gi[e1] + bi[e1]);
}

// ---------------------------------------------------------------------------
extern "C" void kernel_launch(void* const* d_in, const int* in_sizes, int n_in,
                              void* d_out, int out_size, void* d_ws, size_t ws_size,
                              hipStream_t stream) {
    const float2* q  = (const float2*)d_in[0];
    const float2* k  = (const float2*)d_in[1];
    const float2* v  = (const float2*)d_in[2];
    const float2* Wq = (const float2*)d_in[3];
    const float2* bq = (const float2*)d_in[4];
    const float2* Wk = (const float2*)d_in[5];
    const float2* bk = (const float2*)d_in[6];
    const float2* Wv = (const float2*)d_in[7];
    const float2* bv = (const float2*)d_in[8];
    const float*  gr = (const float*)d_in[9];
    const float*  br = (const float*)d_in[10];
    const float*  gi = (const float*)d_in[11];
    const float*  bi = (const float*)d_in[12];

    // workspace (fp16 elements): X planes, W planes, Q/K/V planes, Ob planes
    unsigned short* XP  = (unsigned short*)d_ws;           // 3*2*PL
    unsigned short* WP  = XP + (size_t)6 * PL;             // 3*2*WPL
    unsigned short* QG  = WP + (size_t)6 * WPL;            // 2*PL  [BH][S][64]
    unsigned short* KG  = QG + (size_t)2 * PL;             // 2*PL  [BH][S][64]
    unsigned short* VG  = KG + (size_t)2 * PL;             // 2*PL  [BH][64][S] (transposed)
    unsigned short* ObR = VG + (size_t)2 * PL;             // PL
    unsigned short* ObI = ObR + (size_t)PL;                // PL

    cvt_kernel<<<dim3(4096, 3), 256, 0, stream>>>(q, k, v, XP, PL);
    cvt_kernel<<<dim3(512, 3), 256, 0, stream>>>(Wq, Wk, Wv, WP, WPL);
    proj_kernel<<<dim3(32, 4, 3), 256, 0, stream>>>(XP, WP, bq, bk, bv, QG, KG, VG);
    attn_kernel<<<dim3(512), 256, 0, stream>>>(QG, KG, VG, ObR, ObI);
    ln_kernel<<<dim3(BB * SS), 256, 0, stream>>>(ObR, ObI, q, gr, br, gi, bi, (float2*)d_out);
}

// Round 2
// 207.398 us; speedup vs baseline: 1.0671x; 1.0448x over previous
//
#include <hip/hip_runtime.h>
#include <math.h>

#define BB  4
#define SS  1024
#define DD  512
#define HH  8
#define DHD 64
#define PL  2097152      // elements per Q/K/V/Ob plane (also B*S*D)
#define WPL 262144       // elements per W plane

constexpr float LN_EPS = 1e-5f;

using half4 = __attribute__((ext_vector_type(4))) _Float16;
using half8 = __attribute__((ext_vector_type(8))) _Float16;
using f32x4 = __attribute__((ext_vector_type(4))) float;

__device__ __forceinline__ half8 negh(half8 a) {
    union { half8 h; unsigned int u[4]; } t;
    t.h = a;
    #pragma unroll
    for (int i = 0; i < 4; ++i) t.u[i] ^= 0x80008000u;
    return t.h;
}
// 64-wide swizzled rows (XOR (row&7)<<3, 8-half granules): conflict-free b128
__device__ __forceinline__ half8 ldh64(const unsigned short* p, int row, int col) {
    return *(const half8*)(p + row * 64 + (col ^ ((row & 7) << 3)));
}
#define MFMA16(acc, a, b) acc = __builtin_amdgcn_mfma_f32_16x16x32_f16(a, b, acc, 0, 0, 0)

// ---------------------------------------------------------------------------
// Kernel 0: fp32 complex -> fp16 r/i planes, TILE-BLOCKED layout:
// plane stored as [m/128][d/64][128][64] so proj's K-step strips are 16KB
// contiguous (HBM-stream friendly) instead of 128B-at-1KB-stride.
// Works for X (m=4096) and W (m=512) since D=512 for both.
// ---------------------------------------------------------------------------
__global__ __launch_bounds__(256)
void cvt_kernel(const float2* __restrict__ s0, const float2* __restrict__ s1,
                const float2* __restrict__ s2, unsigned short* __restrict__ dst,
                int planeElems) {
    const int z = blockIdx.y;
    const float2* src = z == 0 ? s0 : (z == 1 ? s1 : s2);
    unsigned short* base = dst + (size_t)z * 2 * planeElems;
    const int idx = (blockIdx.x * 256 + threadIdx.x) * 2;   // complex index (even)
    float4 t = *(const float4*)(src + idx);
    const int m = idx >> 9;          // row
    const int d = idx & 511;         // col (even)
    const int ob = (((m >> 7) << 3) + (d >> 6)) * 8192 + ((m & 127) << 6) + (d & 63);
    union { _Float16 h[2]; unsigned int u; } r, i;
    r.h[0] = (_Float16)t.x; r.h[1] = (_Float16)t.z;
    i.h[0] = (_Float16)t.y; i.h[1] = (_Float16)t.w;
    *(unsigned int*)(base + ob) = r.u;
    *(unsigned int*)(base + planeElems + ob) = i.u;
}

// ---------------------------------------------------------------------------
// Kernel 1: complex projection.
// 128x128 tile, 4 waves in 2x2 (each wave 64x64 -> 128 MFMA vs 32 ds_read
// per K-step). Single-buffered 64KB LDS -> 2 blocks/CU; cross-block overlap
// hides the per-step vmcnt drain (m97 structure).
// Staging: wave w DMAs plane w via global_load_lds width-16. Source is the
// BLOCKED layout (16KB contiguous per plane per step) with the granule
// pre-swizzle (sg^srow) folded into the source address; LDS dest linear;
// ldh64 applies the same involution on read -> conflict-free b128.
// ---------------------------------------------------------------------------
__global__ __launch_bounds__(256, 2)
void proj_kernel(const unsigned short* __restrict__ XP,
                 const unsigned short* __restrict__ WP,
                 const float2* __restrict__ bq, const float2* __restrict__ bk,
                 const float2* __restrict__ bv,
                 unsigned short* __restrict__ QG, unsigned short* __restrict__ KG,
                 unsigned short* __restrict__ VG) {
    const unsigned short* XR = XP + (size_t)blockIdx.z * 2 * PL;
    const unsigned short* XI = XR + PL;
    const unsigned short* WRp = WP + (size_t)blockIdx.z * 2 * WPL;
    const unsigned short* WIp = WRp + WPL;
    const float2* bias; unsigned short* outP;
    if (blockIdx.z == 0)      { bias = bq; outP = QG; }
    else if (blockIdx.z == 1) { bias = bk; outP = KG; }
    else                      { bias = bv; outP = VG; }
    const bool isV = (blockIdx.z == 2);

    // [plane][128 rows][64 k] fp16, single-buffered: 2*16KB + 2*16KB = 64 KiB
    __shared__ __align__(16) unsigned short Xs[2][128 * 64];
    __shared__ __align__(16) unsigned short Ws[2][128 * 64];

    const int tid  = threadIdx.x;
    const int w    = tid >> 6;
    const int lane = tid & 63;
    const int quad = lane >> 4;
    const int l15  = lane & 15;
    const int wm   = w >> 1;                 // m half of the 128x128 tile
    const int we   = w & 1;                  // e half
    const int m0   = blockIdx.x * 128;
    const int e0   = blockIdx.y * 128;

    // ---- staging setup: wave w owns one plane; 16 DMA instrs / K-step ----
    const int srow = lane >> 3;              // 0..7
    const int sg   = lane & 7;               // granule within row
    const unsigned short* gplane;
    unsigned short* lb;
    int row0;
    if (w == 0)      { gplane = XR;  row0 = m0; lb = &Xs[0][0]; }
    else if (w == 1) { gplane = XI;  row0 = m0; lb = &Xs[1][0]; }
    else if (w == 2) { gplane = WRp; row0 = e0; lb = &Ws[0][0]; }
    else             { gplane = WIp; row0 = e0; lb = &Ws[1][0]; }
    // blocked tile base for row0 (multiple of 128) is row0*DD; per-lane source
    // carries the swizzle involution (sg^srow) so linear LDS slot (r, sg)
    // holds global granule sg^(r&7).
    const unsigned short* gs = gplane + (size_t)row0 * DD + srow * 64 + ((sg ^ srow) << 3);

    f32x4 Sr[4][4], Si[4][4];                // [mf][ef]
    #pragma unroll
    for (int a = 0; a < 4; ++a)
        #pragma unroll
        for (int c = 0; c < 4; ++c) { Sr[a][c] = (f32x4)0.f; Si[a][c] = (f32x4)0.f; }

    for (int s = 0; s < 8; ++s) {
        if (s) __syncthreads();              // prev compute done before overwrite
        const unsigned short* _g = gs + (size_t)s * 8192;   // next 16KB block
        #pragma unroll
        for (int j = 0; j < 16; ++j)
            __builtin_amdgcn_global_load_lds(
                (const __attribute__((address_space(1))) void*)(_g + j * 512),
                (__attribute__((address_space(3))) void*)(lb + j * 512),
                16, 0, 0);
        __syncthreads();                     // vmcnt drain -> tile ready

        #pragma unroll
        for (int kc = 0; kc < 2; ++kc) {
            const int dl = kc * 32 + quad * 8;
            half8 xr[4], xi[4];
            #pragma unroll
            for (int mf = 0; mf < 4; ++mf) {
                const int mr = wm * 64 + mf * 16 + l15;
                xr[mf] = ldh64(Xs[0], mr, dl);
                xi[mf] = ldh64(Xs[1], mr, dl);
            }
            #pragma unroll
            for (int ef = 0; ef < 4; ++ef) {
                const int er = we * 64 + ef * 16 + l15;
                half8 wr  = ldh64(Ws[0], er, dl);
                half8 wi  = ldh64(Ws[1], er, dl);
                half8 wmi = negh(wi);
                #pragma unroll
                for (int mf = 0; mf < 4; ++mf) {
                    MFMA16(Sr[mf][ef], xr[mf], wr);    // Xr.Wr
                    MFMA16(Sr[mf][ef], xi[mf], wmi);   // -Xi.Wi
                    MFMA16(Si[mf][ef], xr[mf], wi);    // Xr.Wi
                    MFMA16(Si[mf][ef], xi[mf], wr);    // Xi.Wr
                }
            }
        }
    }

    // ---- epilogue: + bias, fp16, write planes (V transposed) ----
    #pragma unroll
    for (int ef = 0; ef < 4; ++ef) {
        const int eg  = e0 + we * 64 + ef * 16 + l15;   // global out column
        const int hh  = eg >> 6;                         // head
        const int col = eg & 63;
        float2 bb = bias[eg];
        #pragma unroll
        for (int mf = 0; mf < 4; ++mf) {
            #pragma unroll
            for (int reg = 0; reg < 4; ++reg) {
                int m = m0 + wm * 64 + mf * 16 + quad * 4 + reg;
                int bidx = m >> 10;
                int sidx = m & 1023;
                int bh = bidx * HH + hh;
                union { _Float16 h; unsigned short u; } cr, ci;
                cr.h = (_Float16)(Sr[mf][ef][reg] + bb.x);
                ci.h = (_Float16)(Si[mf][ef][reg] + bb.y);
                size_t o = isV ? ((size_t)bh * DHD + col) * SS + sidx
                               : ((size_t)bh * SS + sidx) * DHD + col;
                outP[0 * PL + o] = cr.u;
                outP[1 * PL + o] = ci.u;
            }
        }
    }
}

// ---------------------------------------------------------------------------
// Kernel 2: fp16 MFMA flash attention, S^T formulation. (unchanged)
// ---------------------------------------------------------------------------
#define AWID 72
__global__ __launch_bounds__(256, 2)
void attn_kernel(const unsigned short* __restrict__ QG, const unsigned short* __restrict__ KG,
                 const unsigned short* __restrict__ VG,
                 unsigned short* __restrict__ ObR, unsigned short* __restrict__ ObI) {
    __shared__ unsigned short Ks[2][64 * AWID];   // [r,i][k][d]
    __shared__ unsigned short Vt[2][64 * AWID];   // [r,i][d][k]
    __shared__ unsigned short Ps[2][64 * AWID];   // [r,i][q][k]
    __shared__ float lbuf[2][2][64];              // [plane][k-half][q]

    const int n   = blockIdx.x;
    const int bh  = (n & 7) * 4 + (n >> 7);       // XCD-local bh group
    const int q0  = ((n >> 3) & 15) * 64;
    const int b   = bh >> 3;
    const int h   = bh & 7;

    const int tid  = threadIdx.x;
    const int w    = tid >> 6;
    const int lane = tid & 63;
    const int quad = lane >> 4;
    const int l15  = lane & 15;
    const int sw   = w & 1;        // q-half (both phases)
    const int tw   = w >> 1;       // k-half (scores) / d-half (PV)

    // Q in B-layout registers: lane = q col, quad*8+j = d within 32-window
    half8 qfr[2][2], qfi[2][2], qfmi[2][2];       // [qt][kc]
    #pragma unroll
    for (int qt = 0; qt < 2; ++qt)
        #pragma unroll
        for (int kc = 0; kc < 2; ++kc) {
            size_t qa = ((size_t)bh * SS + q0 + sw * 32 + qt * 16 + l15) * DHD + kc * 32 + quad * 8;
            qfr[qt][kc]  = *(const half8*)(QG + qa);
            qfi[qt][kc]  = *(const half8*)(QG + PL + qa);
            qfmi[qt][kc] = negh(qfi[qt][kc]);
        }

    f32x4 acc[2][2][4];            // [qt][dt][PrVr,PrVi,PiVr,PiVi]
    #pragma unroll
    for (int qt = 0; qt < 2; ++qt)
        #pragma unroll
        for (int dt = 0; dt < 2; ++dt)
            #pragma unroll
            for (int p = 0; p < 4; ++p) acc[qt][dt][p] = (f32x4)0.f;
    float lacc[2][2] = {{0.f, 0.f}, {0.f, 0.f}};  // [qt][plane]

    const int srow = tid >> 3;      // 0..31
    const int sg   = (tid & 7) * 8; // granule col

    for (int kt = 0; kt < SS; kt += 64) {
        __syncthreads();
        // ---- stage K [64k][64d] and V^T [64d][64k] (one row per 8 lanes) ----
        #pragma unroll
        for (int p = 0; p < 2; ++p)
            #pragma unroll
            for (int it = 0; it < 2; ++it) {
                const int r = it * 32 + srow;
                *(uint4*)&Ks[p][r * AWID + sg] =
                    *(const uint4*)(KG + (size_t)p * PL + ((size_t)bh * SS + kt + r) * DHD + sg);
                *(uint4*)&Vt[p][r * AWID + sg] =
                    *(const uint4*)(VG + (size_t)p * PL + ((size_t)bh * DHD + r) * SS + kt + sg);
            }
        __syncthreads();

        // ---- scores: S^T[k32][q32] for this wave's (tw k-half, sw q-half) ----
        f32x4 Sr[2][2], Si[2][2];   // [kt2][qt]
        #pragma unroll
        for (int a = 0; a < 2; ++a)
            #pragma unroll
            for (int c = 0; c < 2; ++c) { Sr[a][c] = (f32x4)0.f; Si[a][c] = (f32x4)0.f; }
        #pragma unroll
        for (int kc = 0; kc < 2; ++kc) {
            #pragma unroll
            for (int kt2 = 0; kt2 < 2; ++kt2) {
                const int krow = tw * 32 + kt2 * 16 + l15;
                half8 akr = *(const half8*)&Ks[0][krow * AWID + kc * 32 + quad * 8];
                half8 aki = *(const half8*)&Ks[1][krow * AWID + kc * 32 + quad * 8];
                #pragma unroll
                for (int qt = 0; qt < 2; ++qt) {
                    MFMA16(Sr[kt2][qt], akr, qfr[qt][kc]);    // K_r . Q_r
                    MFMA16(Sr[kt2][qt], aki, qfmi[qt][kc]);   // -K_i . Q_i
                    MFMA16(Si[kt2][qt], aki, qfr[qt][kc]);    // K_i . Q_r
                    MFMA16(Si[kt2][qt], akr, qfi[qt][kc]);    // K_r . Q_i
                }
            }
        }

        // ---- exp -> P (b64 packed, q-major), l partial per lane ----
        #pragma unroll
        for (int kt2 = 0; kt2 < 2; ++kt2)
            #pragma unroll
            for (int qt = 0; qt < 2; ++qt) {
                half4 pr, pi;
                float sr_ = 0.f, si_ = 0.f;
                #pragma unroll
                for (int reg = 0; reg < 4; ++reg) {
                    float er = __expf(Sr[kt2][qt][reg] * 0.125f);
                    float ei = __expf(Si[kt2][qt][reg] * 0.125f);
                    pr[reg] = (_Float16)er;
                    pi[reg] = (_Float16)ei;
                    sr_ += (float)pr[reg];   // l from rounded p: consistent weights
                    si_ += (float)pi[reg];
                }
                lacc[qt][0] += sr_;
                lacc[qt][1] += si_;
                const int qrow = sw * 32 + qt * 16 + l15;
                const int kcol = tw * 32 + kt2 * 16 + quad * 4;
                *(half4*)&Ps[0][qrow * AWID + kcol] = pr;
                *(half4*)&Ps[1][qrow * AWID + kcol] = pi;
            }
        __syncthreads();

        // ---- PV: out tile q32 (sw) x d32 (tw), k64 accumulation ----
        #pragma unroll
        for (int kc = 0; kc < 2; ++kc) {
            half8 ap[2][2];   // [qt][plane]
            #pragma unroll
            for (int qt = 0; qt < 2; ++qt) {
                const int qrow = sw * 32 + qt * 16 + l15;
                ap[qt][0] = *(const half8*)&Ps[0][qrow * AWID + kc * 32 + quad * 8];
                ap[qt][1] = *(const half8*)&Ps[1][qrow * AWID + kc * 32 + quad * 8];
            }
            #pragma unroll
            for (int dt = 0; dt < 2; ++dt) {
                const int drow = tw * 32 + dt * 16 + l15;
                half8 bvr = *(const half8*)&Vt[0][drow * AWID + kc * 32 + quad * 8];
                half8 bvi = *(const half8*)&Vt[1][drow * AWID + kc * 32 + quad * 8];
                #pragma unroll
                for (int qt = 0; qt < 2; ++qt) {
                    MFMA16(acc[qt][dt][0], ap[qt][0], bvr);
                    MFMA16(acc[qt][dt][1], ap[qt][0], bvi);
                    MFMA16(acc[qt][dt][2], ap[qt][1], bvr);
                    MFMA16(acc[qt][dt][3], ap[qt][1], bvi);
                }
            }
        }
    }

    // ---- combine l: quad-reduce (lane's k-subset -> full k-half), store ----
    __syncthreads();
    #pragma unroll
    for (int qt = 0; qt < 2; ++qt)
        #pragma unroll
        for (int p = 0; p < 2; ++p) {
            float v = lacc[qt][p];
            v += __shfl_xor(v, 16);
            v += __shfl_xor(v, 32);
            if (lane < 16) lbuf[p][tw][sw * 32 + qt * 16 + lane] = v;
        }
    __syncthreads();

    // ---- epilogue: normalize, combine complex, store fp16 planes ----
    #pragma unroll
    for (int qt = 0; qt < 2; ++qt)
        #pragma unroll
        for (int reg = 0; reg < 4; ++reg) {
            const int qloc = sw * 32 + qt * 16 + quad * 4 + reg;
            const float ir = 1.f / (lbuf[0][0][qloc] + lbuf[0][1][qloc]);
            const float ii = 1.f / (lbuf[1][0][qloc] + lbuf[1][1][qloc]);
            #pragma unroll
            for (int dt = 0; dt < 2; ++dt) {
                const int d = tw * 32 + dt * 16 + l15;
                union { _Float16 h; unsigned short u; } cr, ci;
                cr.h = (_Float16)(acc[qt][dt][0][reg] * ir - acc[qt][dt][3][reg] * ii);
                ci.h = (_Float16)(acc[qt][dt][1][reg] * ir + acc[qt][dt][2][reg] * ii);
                size_t o = ((size_t)b * SS + q0 + qloc) * DD + h * DHD + d;
                ObR[o] = cr.u;
                ObI[o] = ci.u;
            }
        }
}

// ---------------------------------------------------------------------------
// Kernel 3: residual + dual LayerNorm over D (biased var, eps inside sqrt)
// ---------------------------------------------------------------------------
__global__ __launch_bounds__(256)
void ln_kernel(const unsigned short* __restrict__ OrP, const unsigned short* __restrict__ OiP,
               const float2* __restrict__ Qin,
               const float* __restrict__ gr, const float* __restrict__ br,
               const float* __restrict__ gi, const float* __restrict__ bi,
               float2* __restrict__ out) {
    const int row = blockIdx.x;           // b*S + s
    const int tid = threadIdx.x;
    const size_t base = (size_t)row * DD;
    const int e0 = 2 * tid, e1 = 2 * tid + 1;

    union { unsigned int u; _Float16 h[2]; } tr, ti;
    tr.u = *(const unsigned int*)(OrP + base + e0);
    ti.u = *(const unsigned int*)(OiP + base + e0);
    float2 r0 = Qin[base + e0];
    float2 r1 = Qin[base + e1];
    float xr0 = (float)tr.h[0] + r0.x;
    float xr1 = (float)tr.h[1] + r1.x;
    float xi0 = (float)ti.h[0] + r0.y;
    float xi1 = (float)ti.h[1] + r1.y;

    float sr = xr0 + xr1;
    float si = xi0 + xi1;
    float qr = xr0 * xr0 + xr1 * xr1;
    float qi = xi0 * xi0 + xi1 * xi1;
    #pragma unroll
    for (int off = 32; off > 0; off >>= 1) {
        sr += __shfl_down(sr, off);
        si += __shfl_down(si, off);
        qr += __shfl_down(qr, off);
        qi += __shfl_down(qi, off);
    }
    __shared__ float red[4][4];
    __shared__ float stat[4];
    int lane = tid & 63, wid = tid >> 6;
    if (lane == 0) { red[wid][0] = sr; red[wid][1] = si; red[wid][2] = qr; red[wid][3] = qi; }
    __syncthreads();
    if (tid == 0) {
        sr = red[0][0] + red[1][0] + red[2][0] + red[3][0];
        si = red[0][1] + red[1][1] + red[2][1] + red[3][1];
        qr = red[0][2] + red[1][2] + red[2][2] + red[3][2];
        qi = red[0][3] + red[1][3] + red[2][3] + red[3][3];
        float mur = sr * (1.f / DD), mui = si * (1.f / DD);
        float vr = qr * (1.f / DD) - mur * mur;
        float vi = qi * (1.f / DD) - mui * mui;
        stat[0] = mur; stat[1] = mui;
        stat[2] = rsqrtf(vr + LN_EPS); stat[3] = rsqrtf(vi + LN_EPS);
    }
    __syncthreads();
    float mur = stat[0], mui = stat[1], rsr = stat[2], rsi = stat[3];
    out[base + e0] = make_float2((xr0 - mur) * rsr * gr[e0] + br[e0],
                                 (xi0 - mui) * rsi * gi[e0] + bi[e0]);
    out[base + e1] = make_float2((xr1 - mur) * rsr * gr[e1] + br[e1],
                                 (xi1 - mui) * rsi * gi[e1] + bi[e1]);
}

// ---------------------------------------------------------------------------
extern "C" void kernel_launch(void* const* d_in, const int* in_sizes, int n_in,
                              void* d_out, int out_size, void* d_ws, size_t ws_size,
                              hipStream_t stream) {
    const float2* q  = (const float2*)d_in[0];
    const float2* k  = (const float2*)d_in[1];
    const float2* v  = (const float2*)d_in[2];
    const float2* Wq = (const float2*)d_in[3];
    const float2* bq = (const float2*)d_in[4];
    const float2* Wk = (const float2*)d_in[5];
    const float2* bk = (const float2*)d_in[6];
    const float2* Wv = (const float2*)d_in[7];
    const float2* bv = (const float2*)d_in[8];
    const float*  gr = (const float*)d_in[9];
    const float*  br = (const float*)d_in[10];
    const float*  gi = (const float*)d_in[11];
    const float*  bi = (const float*)d_in[12];

    // workspace (fp16 elements): X planes, W planes, Q/K/V planes, Ob planes
    unsigned short* XP  = (unsigned short*)d_ws;           // 3*2*PL (blocked)
    unsigned short* WP  = XP + (size_t)6 * PL;             // 3*2*WPL (blocked)
    unsigned short* QG  = WP + (size_t)6 * WPL;            // 2*PL  [BH][S][64]
    unsigned short* KG  = QG + (size_t)2 * PL;             // 2*PL  [BH][S][64]
    unsigned short* VG  = KG + (size_t)2 * PL;             // 2*PL  [BH][64][S] (transposed)
    unsigned short* ObR = VG + (size_t)2 * PL;             // PL
    unsigned short* ObI = ObR + (size_t)PL;                // PL

    cvt_kernel<<<dim3(4096, 3), 256, 0, stream>>>(q, k, v, XP, PL);
    cvt_kernel<<<dim3(512, 3), 256, 0, stream>>>(Wq, Wk, Wv, WP, WPL);
    proj_kernel<<<dim3(32, 4, 3), 256, 0, stream>>>(XP, WP, bq, bk, bv, QG, KG, VG);
    attn_kernel<<<dim3(512), 256, 0, stream>>>(QG, KG, VG, ObR, ObI);
    ln_kernel<<<dim3(BB * SS), 256, 0, stream>>>(ObR, ObI, q, gr, br, gi, bi, (float2*)d_out);
}